// Round 9
// baseline (739.203 us; speedup 1.0000x reference)
//
#include <hip/hip_runtime.h>
#include <hip/hip_bf16.h>

typedef float f32x4 __attribute__((ext_vector_type(4)));
typedef short bf16x8 __attribute__((ext_vector_type(8)));

#define NB 50000
#define NK 32
#define NH 128
#define NL 64

static __device__ __forceinline__ unsigned short f2bf(float f) {
    unsigned int u = __float_as_uint(f);
    u += 0x7fffu + ((u >> 16) & 1u);
    return (unsigned short)(u >> 16);
}
static __device__ __forceinline__ float bf2f(unsigned short u) {
    return __uint_as_float(((unsigned int)u) << 16);
}
static __device__ __forceinline__ float bflo(unsigned int u) { return __uint_as_float(u << 16); }
static __device__ __forceinline__ float bfhi(unsigned int u) { return __uint_as_float(u & 0xffff0000u); }

__global__ void kl_zero_kernel(float* out) {
    if (threadIdx.x == 0 && blockIdx.x == 0) out[(size_t)NB * NH] = 0.0f;
}

// ---------------- K0: Wvo = Wv@Wo (f32, ws), bvo = b_v@Wo + b_o ----------------
__global__ void __launch_bounds__(256) wvo_kernel(const float* __restrict__ W_v,
                                                  const float* __restrict__ W_o,
                                                  const float* __restrict__ b_v,
                                                  const float* __restrict__ b_o,
                                                  float* __restrict__ wvo_ws,
                                                  float* __restrict__ bvo_ws)
{
    const int t = threadIdx.x;
    for (int e = t; e < 64 * 128; e += 256) {
        int d = e >> 7, h = e & 127;
        float s = 0.f;
#pragma unroll 8
        for (int c = 0; c < 64; ++c) s += W_v[d * 64 + c] * W_o[c * 128 + h];
        wvo_ws[e] = s;
    }
    if (t < 128) {
        float s = b_o[t];
#pragma unroll 8
        for (int c = 0; c < 64; ++c) s += b_v[c] * W_o[c * 128 + t];
        bvo_ws[t] = s;
    }
}

// ---------------- K1: qk = (self@Wq + b_q) @ Wk^T   (f32 out to ws) ----------------
__global__ void __launch_bounds__(256) qk_kernel(const float* __restrict__ self_feat,
                                                 const float* __restrict__ W_q,
                                                 const float* __restrict__ b_q,
                                                 const float* __restrict__ W_k,
                                                 float* __restrict__ qk_ws)
{
    __shared__ __align__(16) unsigned short A[32 * 128];
    __shared__ __align__(16) unsigned short ZQ[32 * 64];
    const int t = threadIdx.x, w = t >> 6, l = t & 63, g = l >> 4, li = l & 15;

    bf16x8 Bq[4];
#pragma unroll
    for (int s = 0; s < 4; ++s) {
        int k0 = 32 * s + 8 * g, c = li + 16 * w;
        bf16x8 f;
#pragma unroll
        for (int j = 0; j < 8; ++j) f[j] = (short)f2bf(W_q[(k0 + j) * 64 + c]);
        Bq[s] = f;
    }
    bf16x8 Bk[2];
#pragma unroll
    for (int s = 0; s < 2; ++s) {
        int k0 = 32 * s + 8 * g, d = li + 16 * w;
        bf16x8 f;
#pragma unroll
        for (int j = 0; j < 8; ++j) f[j] = (short)f2bf(W_k[d * 64 + k0 + j]);
        Bk[s] = f;
    }
    const float bq = b_q[li + 16 * w];
    const int n0 = blockIdx.x * 32;

    {
        int row = t >> 3, c0 = (t & 7) * 16;
        float x[16];
        if (n0 + row < NB) {
            const float* src = self_feat + (size_t)(n0 + row) * NH + c0;
#pragma unroll
            for (int i = 0; i < 4; ++i) {
                float4 v4 = ((const float4*)src)[i];
                x[4 * i] = v4.x; x[4 * i + 1] = v4.y; x[4 * i + 2] = v4.z; x[4 * i + 3] = v4.w;
            }
        } else {
#pragma unroll
            for (int i = 0; i < 16; ++i) x[i] = 0.f;
        }
        alignas(16) unsigned short yb[16];
#pragma unroll
        for (int i = 0; i < 16; ++i) yb[i] = f2bf(x[i]);
        int boff = row * 256 + c0 * 2;
        *(int4*)((char*)A + ((boff) ^ ((row & 7) << 4))) = *(int4*)&yb[0];
        *(int4*)((char*)A + ((boff + 16) ^ ((row & 7) << 4))) = *(int4*)&yb[8];
    }
    __syncthreads();

    const f32x4 zero4 = {0.f, 0.f, 0.f, 0.f};
    f32x4 acc[2] = {zero4, zero4};
#pragma unroll
    for (int s = 0; s < 4; ++s) {
        bf16x8 A0 = *(const bf16x8*)((const char*)A + ((li * 256 + s * 64 + g * 16) ^ ((li & 7) << 4)));
        bf16x8 A1 = *(const bf16x8*)((const char*)A + (((16 + li) * 256 + s * 64 + g * 16) ^ ((li & 7) << 4)));
        acc[0] = __builtin_amdgcn_mfma_f32_16x16x32_bf16(A0, Bq[s], acc[0], 0, 0, 0);
        acc[1] = __builtin_amdgcn_mfma_f32_16x16x32_bf16(A1, Bq[s], acc[1], 0, 0, 0);
    }
#pragma unroll
    for (int mt = 0; mt < 2; ++mt)
#pragma unroll
        for (int r = 0; r < 4; ++r) {
            int row = 16 * mt + 4 * g + r, c = li + 16 * w;
            *(unsigned short*)((char*)ZQ + ((row * 128 + c * 2) ^ ((row & 7) << 4))) = f2bf(acc[mt][r] + bq);
        }
    __syncthreads();

    f32x4 acc2[2] = {zero4, zero4};
#pragma unroll
    for (int s = 0; s < 2; ++s) {
        bf16x8 A0 = *(const bf16x8*)((const char*)ZQ + ((li * 128 + s * 64 + g * 16) ^ ((li & 7) << 4)));
        bf16x8 A1 = *(const bf16x8*)((const char*)ZQ + (((16 + li) * 128 + s * 64 + g * 16) ^ ((li & 7) << 4)));
        acc2[0] = __builtin_amdgcn_mfma_f32_16x16x32_bf16(A0, Bk[s], acc2[0], 0, 0, 0);
        acc2[1] = __builtin_amdgcn_mfma_f32_16x16x32_bf16(A1, Bk[s], acc2[1], 0, 0, 0);
    }
#pragma unroll
    for (int mt = 0; mt < 2; ++mt)
#pragma unroll
        for (int r = 0; r < 4; ++r) {
            int row = 16 * mt + 4 * g + r;
            if (n0 + row < NB)
                qk_ws[(size_t)(n0 + row) * 64 + li + 16 * w] = acc2[mt][r];
        }
}

// ---------------- K2: fused main — 8 nodes/block cooperative, 4 barriers/node ----------
__global__ void __launch_bounds__(256, 3) fz9_kernel(
    const float* __restrict__ neighbor_feat, const float* __restrict__ trust_mask,
    const float* __restrict__ eps_g,
    const float* __restrict__ pre_g, const float* __restrict__ pre_b,
    const float* __restrict__ W_mu, const float* __restrict__ b_mu,
    const float* __restrict__ W_lv, const float* __restrict__ b_lv,
    const float* __restrict__ post_g, const float* __restrict__ post_b,
    const float* __restrict__ qk_ws, const float* __restrict__ wvo_ws,
    const float* __restrict__ bvo_ws,
    float* __restrict__ out)
{
    __shared__ __align__(16) unsigned short A[32 * 128];  // 8KB bf16 swizzled
    __shared__ float muv[32 * 132];                       // 16.9KB f32, stride 132 (optimal banks)
    __shared__ float2 s_pgb[128];                         // 1KB
    __shared__ float s_bmu[64], s_blv[64], s_pg[64], s_pb[64];
    __shared__ float logit_l[32];
    __shared__ float zpart[4][64];
    __shared__ float klw[4];

    const int t = threadIdx.x, w = t >> 6, l = t & 63, g = l >> 4, li = l & 15;

    if (t < 128) s_pgb[t] = make_float2(pre_g[t], pre_b[t]);
    if (t < 64) { s_bmu[t] = b_mu[t]; s_blv[t] = b_lv[t]; s_pg[t] = post_g[t]; s_pb[t] = post_b[t]; }

    // GEMM1 B-frags: waves 0,1 -> W_mu cols 0-31/32-63; waves 2,3 -> W_lv (muv cols 64-127)
    bf16x8 Wml[2][4];
    {
        const float* Wsrc = (w < 2) ? W_mu : W_lv;
        int cb = 32 * (w & 1) + li;
#pragma unroll
        for (int ntp = 0; ntp < 2; ++ntp)
#pragma unroll
            for (int s = 0; s < 4; ++s) {
                int k0 = 32 * s + 8 * g, c = cb + 16 * ntp;
                bf16x8 f;
#pragma unroll
                for (int j = 0; j < 8; ++j) f[j] = (short)f2bf(Wsrc[(k0 + j) * 64 + c]);
                Wml[ntp][s] = f;
            }
    }
    // out-proj frags: wave w -> h = 32w + (l&31); lane half picks c-window
    const int h = 32 * w + (l & 31);
    const int chalf = l >> 5;
    unsigned int wvo_pk[16];
#pragma unroll
    for (int j = 0; j < 16; ++j) {
        int c = 32 * chalf + 2 * j;
        wvo_pk[j] = (unsigned)f2bf(wvo_ws[c * 128 + h]) | ((unsigned)f2bf(wvo_ws[(c + 1) * 128 + h]) << 16);
    }
    const float bvo_r = bvo_ws[h];
    __syncthreads();

    const int row = t >> 3;          // 0..31
    const int c0 = (t & 7) * 16;     // P0 col group (128 cols)
    const int l0 = (t & 7) * 8;      // P2 col group (64 cols)
    int bn = blockIdx.x * 8;         // 6250 * 8 = 50000 exact

    float x[16], ee[8], qk8[8], trr;
    {   // prologue prefetch
        const float* src = neighbor_feat + ((size_t)bn * NK + row) * NH + c0;
#pragma unroll
        for (int i = 0; i < 4; ++i) {
            float4 v4 = ((const float4*)src)[i];
            x[4 * i] = v4.x; x[4 * i + 1] = v4.y; x[4 * i + 2] = v4.z; x[4 * i + 3] = v4.w;
        }
        const float* ep = eps_g + ((size_t)bn * NK + row) * NL + l0;
        float4 e0 = ((const float4*)ep)[0], e1 = ((const float4*)ep)[1];
        ee[0] = e0.x; ee[1] = e0.y; ee[2] = e0.z; ee[3] = e0.w;
        ee[4] = e1.x; ee[5] = e1.y; ee[6] = e1.z; ee[7] = e1.w;
        const float* qp = qk_ws + (size_t)bn * 64 + l0;
        float4 q0 = ((const float4*)qp)[0], q1 = ((const float4*)qp)[1];
        qk8[0] = q0.x; qk8[1] = q0.y; qk8[2] = q0.z; qk8[3] = q0.w;
        qk8[4] = q1.x; qk8[5] = q1.y; qk8[6] = q1.z; qk8[7] = q1.w;
        trr = trust_mask[(size_t)bn * NK + row];
    }

    float kl_acc = 0.f;
    const f32x4 zero4 = {0.f, 0.f, 0.f, 0.f};

#pragma unroll 1
    for (int i = 0; i < 8; ++i, ++bn) {
        const int bnx = (i < 7) ? bn + 1 : bn;

        // ---- P0: pre-LN -> bf16 A tile; reissue x ----
        float s1 = 0.f;
#pragma unroll
        for (int j = 0; j < 16; ++j) s1 += x[j];
        s1 += __shfl_xor(s1, 1); s1 += __shfl_xor(s1, 2); s1 += __shfl_xor(s1, 4);
        float mean = s1 * (1.f / 128.f);
        float s2 = 0.f;
#pragma unroll
        for (int j = 0; j < 16; ++j) { float d = x[j] - mean; s2 += d * d; }
        s2 += __shfl_xor(s2, 1); s2 += __shfl_xor(s2, 2); s2 += __shfl_xor(s2, 4);
        float inv = rsqrtf(s2 * (1.f / 128.f) + 1e-5f);
        alignas(16) unsigned short yb[16];
#pragma unroll
        for (int j = 0; j < 16; ++j) {
            float2 gb = s_pgb[c0 + j];
            yb[j] = f2bf((x[j] - mean) * inv * gb.x + gb.y);
        }
        {
            int boff = row * 256 + c0 * 2;
            *(int4*)((char*)A + ((boff) ^ ((row & 7) << 4))) = *(int4*)&yb[0];
            *(int4*)((char*)A + ((boff + 16) ^ ((row & 7) << 4))) = *(int4*)&yb[8];
        }
        {
            const float* src = neighbor_feat + ((size_t)bnx * NK + row) * NH + c0;
#pragma unroll
            for (int j = 0; j < 4; ++j) {
                float4 v4 = ((const float4*)src)[j];
                x[4 * j] = v4.x; x[4 * j + 1] = v4.y; x[4 * j + 2] = v4.z; x[4 * j + 3] = v4.w;
            }
        }
        __syncthreads();   // b1

        // ---- P1: GEMM1, wave w -> cols 32w..32w+31 of [mu|lv]; write muv ----
        {
            f32x4 acc[2][2];
            acc[0][0] = zero4; acc[0][1] = zero4; acc[1][0] = zero4; acc[1][1] = zero4;
#pragma unroll
            for (int s = 0; s < 4; ++s) {
                bf16x8 A0 = *(const bf16x8*)((const char*)A + ((li * 256 + s * 64 + g * 16) ^ ((li & 7) << 4)));
                bf16x8 A1 = *(const bf16x8*)((const char*)A + (((16 + li) * 256 + s * 64 + g * 16) ^ ((li & 7) << 4)));
#pragma unroll
                for (int ntp = 0; ntp < 2; ++ntp) {
                    acc[0][ntp] = __builtin_amdgcn_mfma_f32_16x16x32_bf16(A0, Wml[ntp][s], acc[0][ntp], 0, 0, 0);
                    acc[1][ntp] = __builtin_amdgcn_mfma_f32_16x16x32_bf16(A1, Wml[ntp][s], acc[1][ntp], 0, 0, 0);
                }
            }
#pragma unroll
            for (int mt = 0; mt < 2; ++mt)
#pragma unroll
                for (int ntp = 0; ntp < 2; ++ntp)
#pragma unroll
                    for (int r = 0; r < 4; ++r)
                        muv[(16 * mt + 4 * g + r) * 132 + 32 * w + 16 * ntp + li] = acc[mt][ntp][r];
        }
        __syncthreads();   // b2

        // ---- P2: reparam + KL + post-LN + logit partial ----
        float zr[8];
        {
            f32x4 mu0 = *(const f32x4*)&muv[row * 132 + l0];
            f32x4 mu1 = *(const f32x4*)&muv[row * 132 + l0 + 4];
            f32x4 lv0 = *(const f32x4*)&muv[row * 132 + 64 + l0];
            f32x4 lv1 = *(const f32x4*)&muv[row * 132 + 64 + l0 + 4];
#pragma unroll
            for (int j = 0; j < 8; ++j) {
                float mu = ((j < 4) ? mu0[j & 3] : mu1[j & 3]) + s_bmu[l0 + j];
                float lv = ((j < 4) ? lv0[j & 3] : lv1[j & 3]) + s_blv[l0 + j];
                float eh = __expf(0.5f * lv);
                kl_acc += 1.f + lv - mu * mu - eh * eh;
                zr[j] = mu + ee[j] * eh;
            }
        }
        {   // reissue eps
            const float* ep = eps_g + ((size_t)bnx * NK + row) * NL + l0;
            float4 e0 = ((const float4*)ep)[0], e1 = ((const float4*)ep)[1];
            ee[0] = e0.x; ee[1] = e0.y; ee[2] = e0.z; ee[3] = e0.w;
            ee[4] = e1.x; ee[5] = e1.y; ee[6] = e1.z; ee[7] = e1.w;
        }
        {
            float zs = 0.f;
#pragma unroll
            for (int j = 0; j < 8; ++j) zs += zr[j];
            zs += __shfl_xor(zs, 1); zs += __shfl_xor(zs, 2); zs += __shfl_xor(zs, 4);
            float zm = zs * (1.f / 64.f);
            float zv = 0.f;
#pragma unroll
            for (int j = 0; j < 8; ++j) { float d = zr[j] - zm; zv += d * d; }
            zv += __shfl_xor(zv, 1); zv += __shfl_xor(zv, 2); zv += __shfl_xor(zv, 4);
            float zi = rsqrtf(zv * (1.f / 64.f) + 1e-5f);
#pragma unroll
            for (int j = 0; j < 8; ++j)
                zr[j] = (zr[j] - zm) * zi * s_pg[l0 + j] + s_pb[l0 + j];
        }
        {   // logit[row]
            float lg = 0.f;
#pragma unroll
            for (int j = 0; j < 8; ++j) lg += zr[j] * qk8[j];
            lg += __shfl_xor(lg, 1); lg += __shfl_xor(lg, 2); lg += __shfl_xor(lg, 4);
            if ((t & 7) == 0) logit_l[row] = lg * 0.125f + __logf(trr + 1e-6f);
        }
        {   // reissue qk + trust
            const float* qp = qk_ws + (size_t)bnx * 64 + l0;
            float4 q0 = ((const float4*)qp)[0], q1 = ((const float4*)qp)[1];
            qk8[0] = q0.x; qk8[1] = q0.y; qk8[2] = q0.z; qk8[3] = q0.w;
            qk8[4] = q1.x; qk8[5] = q1.y; qk8[6] = q1.z; qk8[7] = q1.w;
            trr = trust_mask[(size_t)bnx * NK + row];
        }
        __syncthreads();   // b3

        // ---- P3: wave-parallel softmax + zbar wave-partials ----
        {
            float lgv = logit_l[l & 31];
            float mx = lgv;
            mx = fmaxf(mx, __shfl_xor(mx, 1));  mx = fmaxf(mx, __shfl_xor(mx, 2));
            mx = fmaxf(mx, __shfl_xor(mx, 4));  mx = fmaxf(mx, __shfl_xor(mx, 8));
            mx = fmaxf(mx, __shfl_xor(mx, 16));
            float ev = __expf(lgv - mx);
            float den = ev;
            den += __shfl_xor(den, 1); den += __shfl_xor(den, 2);
            den += __shfl_xor(den, 4); den += __shfl_xor(den, 8);
            den += __shfl_xor(den, 16);
            float att_own = __expf(logit_l[row] - mx) / den;
            float av[8];
#pragma unroll
            for (int j = 0; j < 8; ++j) av[j] = att_own * zr[j];
#pragma unroll
            for (int j = 0; j < 8; ++j) {
                av[j] += __shfl_xor(av[j], 8);
                av[j] += __shfl_xor(av[j], 16);
                av[j] += __shfl_xor(av[j], 32);
            }
            if (l < 8) {
                float4 p0 = {av[0], av[1], av[2], av[3]};
                float4 p1 = {av[4], av[5], av[6], av[7]};
                ((float4*)&zpart[w][8 * l])[0] = p0;
                ((float4*)&zpart[w][8 * l])[1] = p1;
            }
        }
        __syncthreads();   // b4

        // ---- P4: out = zbar @ Wvo + bvo (per-wave h-slice; zpart summed in-loop) ----
        {
            float o = 0.f;
#pragma unroll
            for (int j = 0; j < 16; ++j) {
                int c = 32 * chalf + 2 * j;
                float2 z0 = *(const float2*)&zpart[0][c];
                float2 z1 = *(const float2*)&zpart[1][c];
                float2 z2 = *(const float2*)&zpart[2][c];
                float2 z3 = *(const float2*)&zpart[3][c];
                float zs0 = z0.x + z1.x + z2.x + z3.x;
                float zs1 = z0.y + z1.y + z2.y + z3.y;
                o += zs0 * bflo(wvo_pk[j]) + zs1 * bfhi(wvo_pk[j]);
            }
            o += __shfl_xor(o, 32);
            if (l < 32) out[(size_t)bn * NH + h] = o + bvo_r;
        }
        // no barrier: next P0 touches only A/x (readers finished before b2);
        // zpart next written after next b3 (all waves passed b1' => finished P4)
    }

    // ---- KL reduction ----
#pragma unroll
    for (int msk = 1; msk < 64; msk <<= 1) kl_acc += __shfl_xor(kl_acc, msk);
    if (l == 0) klw[w] = kl_acc;
    __syncthreads();
    if (t == 0) {
        float tot = klw[0] + klw[1] + klw[2] + klw[3];
        atomicAdd(out + (size_t)NB * NH, tot * (-0.5f * 0.001f / ((float)NB * NK)));
    }
}

extern "C" void kernel_launch(void* const* d_in, const int* in_sizes, int n_in,
                              void* d_out, int out_size, void* d_ws, size_t ws_size,
                              hipStream_t stream) {
    const float* self_feat     = (const float*)d_in[0];
    const float* neighbor_feat = (const float*)d_in[1];
    const float* trust_mask    = (const float*)d_in[2];
    const float* eps           = (const float*)d_in[3];
    const float* pre_g  = (const float*)d_in[4];
    const float* pre_b  = (const float*)d_in[5];
    const float* W_mu   = (const float*)d_in[6];
    const float* b_mu   = (const float*)d_in[7];
    const float* W_lv   = (const float*)d_in[8];
    const float* b_lv   = (const float*)d_in[9];
    const float* post_g = (const float*)d_in[10];
    const float* post_b = (const float*)d_in[11];
    const float* W_q    = (const float*)d_in[12];
    const float* b_q    = (const float*)d_in[13];
    const float* W_k    = (const float*)d_in[14];
    const float* W_v    = (const float*)d_in[16];
    const float* b_v    = (const float*)d_in[17];
    const float* W_o    = (const float*)d_in[18];
    const float* b_o    = (const float*)d_in[19];
    float* out = (float*)d_out;

    // ws: qk f32 [NB,64] (12.8MB) | Wvo f32 [64,128] | bvo f32 [128]
    float* qk_ws  = (float*)d_ws;
    float* wvo_ws = qk_ws + (size_t)NB * 64;
    float* bvo_ws = wvo_ws + 64 * 128;

    hipLaunchKernelGGL(kl_zero_kernel, dim3(1), dim3(64), 0, stream, out);
    hipLaunchKernelGGL(wvo_kernel, dim3(1), dim3(256), 0, stream, W_v, W_o, b_v, b_o, wvo_ws, bvo_ws);
    hipLaunchKernelGGL(qk_kernel, dim3((NB + 31) / 32), dim3(256), 0, stream,
                       self_feat, W_q, b_q, W_k, qk_ws);
    hipLaunchKernelGGL(fz9_kernel, dim3(NB / 8), dim3(256), 0, stream,
                       neighbor_feat, trust_mask, eps, pre_g, pre_b,
                       W_mu, b_mu, W_lv, b_lv, post_g, post_b,
                       qk_ws, wvo_ws, bvo_ws, out);
}

// Round 10
// 522.066 us; speedup vs baseline: 1.4159x; 1.4159x over previous
//
#include <hip/hip_runtime.h>
#include <hip/hip_bf16.h>

typedef float f32x4 __attribute__((ext_vector_type(4)));
typedef short bf16x8 __attribute__((ext_vector_type(8)));

#define NB 50000
#define NK 32
#define NH 128
#define NL 64

static __device__ __forceinline__ unsigned short f2bf(float f) {
    unsigned int u = __float_as_uint(f);
    u += 0x7fffu + ((u >> 16) & 1u);
    return (unsigned short)(u >> 16);
}
static __device__ __forceinline__ float bf2f(unsigned short u) {
    return __uint_as_float(((unsigned int)u) << 16);
}
static __device__ __forceinline__ float bflo(unsigned int u) { return __uint_as_float(u << 16); }
static __device__ __forceinline__ float bfhi(unsigned int u) { return __uint_as_float(u & 0xffff0000u); }

__global__ void kl_zero_kernel(float* out) {
    if (threadIdx.x == 0 && blockIdx.x == 0) out[(size_t)NB * NH] = 0.0f;
}

// ---------------- K0: Wvo = Wv@Wo (f32, ws), bvo = b_v@Wo + b_o ----------------
__global__ void __launch_bounds__(256) wvo_kernel(const float* __restrict__ W_v,
                                                  const float* __restrict__ W_o,
                                                  const float* __restrict__ b_v,
                                                  const float* __restrict__ b_o,
                                                  float* __restrict__ wvo_ws,
                                                  float* __restrict__ bvo_ws)
{
    const int t = threadIdx.x;
    for (int e = t; e < 64 * 128; e += 256) {
        int d = e >> 7, h = e & 127;
        float s = 0.f;
#pragma unroll 8
        for (int c = 0; c < 64; ++c) s += W_v[d * 64 + c] * W_o[c * 128 + h];
        wvo_ws[e] = s;
    }
    if (t < 128) {
        float s = b_o[t];
#pragma unroll 8
        for (int c = 0; c < 64; ++c) s += b_v[c] * W_o[c * 128 + t];
        bvo_ws[t] = s;
    }
}

// ---------------- K1: qk = (self@Wq + b_q) @ Wk^T   (f32 out to ws) ----------------
__global__ void __launch_bounds__(256) qk_kernel(const float* __restrict__ self_feat,
                                                 const float* __restrict__ W_q,
                                                 const float* __restrict__ b_q,
                                                 const float* __restrict__ W_k,
                                                 float* __restrict__ qk_ws)
{
    __shared__ __align__(16) unsigned short A[32 * 128];
    __shared__ __align__(16) unsigned short ZQ[32 * 64];
    const int t = threadIdx.x, w = t >> 6, l = t & 63, g = l >> 4, li = l & 15;

    bf16x8 Bq[4];
#pragma unroll
    for (int s = 0; s < 4; ++s) {
        int k0 = 32 * s + 8 * g, c = li + 16 * w;
        bf16x8 f;
#pragma unroll
        for (int j = 0; j < 8; ++j) f[j] = (short)f2bf(W_q[(k0 + j) * 64 + c]);
        Bq[s] = f;
    }
    bf16x8 Bk[2];
#pragma unroll
    for (int s = 0; s < 2; ++s) {
        int k0 = 32 * s + 8 * g, d = li + 16 * w;
        bf16x8 f;
#pragma unroll
        for (int j = 0; j < 8; ++j) f[j] = (short)f2bf(W_k[d * 64 + k0 + j]);
        Bk[s] = f;
    }
    const float bq = b_q[li + 16 * w];
    const int n0 = blockIdx.x * 32;

    {
        int row = t >> 3, c0 = (t & 7) * 16;
        float x[16];
        if (n0 + row < NB) {
            const float* src = self_feat + (size_t)(n0 + row) * NH + c0;
#pragma unroll
            for (int i = 0; i < 4; ++i) {
                float4 v4 = ((const float4*)src)[i];
                x[4 * i] = v4.x; x[4 * i + 1] = v4.y; x[4 * i + 2] = v4.z; x[4 * i + 3] = v4.w;
            }
        } else {
#pragma unroll
            for (int i = 0; i < 16; ++i) x[i] = 0.f;
        }
        alignas(16) unsigned short yb[16];
#pragma unroll
        for (int i = 0; i < 16; ++i) yb[i] = f2bf(x[i]);
        int boff = row * 256 + c0 * 2;
        *(int4*)((char*)A + ((boff) ^ ((row & 7) << 4))) = *(int4*)&yb[0];
        *(int4*)((char*)A + ((boff + 16) ^ ((row & 7) << 4))) = *(int4*)&yb[8];
    }
    __syncthreads();

    const f32x4 zero4 = {0.f, 0.f, 0.f, 0.f};
    f32x4 acc[2] = {zero4, zero4};
#pragma unroll
    for (int s = 0; s < 4; ++s) {
        bf16x8 A0 = *(const bf16x8*)((const char*)A + ((li * 256 + s * 64 + g * 16) ^ ((li & 7) << 4)));
        bf16x8 A1 = *(const bf16x8*)((const char*)A + (((16 + li) * 256 + s * 64 + g * 16) ^ ((li & 7) << 4)));
        acc[0] = __builtin_amdgcn_mfma_f32_16x16x32_bf16(A0, Bq[s], acc[0], 0, 0, 0);
        acc[1] = __builtin_amdgcn_mfma_f32_16x16x32_bf16(A1, Bq[s], acc[1], 0, 0, 0);
    }
#pragma unroll
    for (int mt = 0; mt < 2; ++mt)
#pragma unroll
        for (int r = 0; r < 4; ++r) {
            int row = 16 * mt + 4 * g + r, c = li + 16 * w;
            *(unsigned short*)((char*)ZQ + ((row * 128 + c * 2) ^ ((row & 7) << 4))) = f2bf(acc[mt][r] + bq);
        }
    __syncthreads();

    f32x4 acc2[2] = {zero4, zero4};
#pragma unroll
    for (int s = 0; s < 2; ++s) {
        bf16x8 A0 = *(const bf16x8*)((const char*)ZQ + ((li * 128 + s * 64 + g * 16) ^ ((li & 7) << 4)));
        bf16x8 A1 = *(const bf16x8*)((const char*)ZQ + (((16 + li) * 128 + s * 64 + g * 16) ^ (((16 + li) & 7) << 4)));
        acc2[0] = __builtin_amdgcn_mfma_f32_16x16x32_bf16(A0, Bk[s], acc2[0], 0, 0, 0);
        acc2[1] = __builtin_amdgcn_mfma_f32_16x16x32_bf16(A1, Bk[s], acc2[1], 0, 0, 0);
    }
#pragma unroll
    for (int mt = 0; mt < 2; ++mt)
#pragma unroll
        for (int r = 0; r < 4; ++r) {
            int row = 16 * mt + 4 * g + r;
            if (n0 + row < NB)
                qk_ws[(size_t)(n0 + row) * 64 + li + 16 * w] = acc2[mt][r];
        }
}

// ---------------- K2: fused main — 8 nodes/block cooperative, 4 barriers/node ----------
__global__ void __launch_bounds__(256) fz10_kernel(
    const float* __restrict__ neighbor_feat, const float* __restrict__ trust_mask,
    const float* __restrict__ eps_g,
    const float* __restrict__ pre_g, const float* __restrict__ pre_b,
    const float* __restrict__ W_mu, const float* __restrict__ b_mu,
    const float* __restrict__ W_lv, const float* __restrict__ b_lv,
    const float* __restrict__ post_g, const float* __restrict__ post_b,
    const float* __restrict__ qk_ws, const float* __restrict__ wvo_ws,
    const float* __restrict__ bvo_ws,
    float* __restrict__ out)
{
    __shared__ __align__(16) unsigned short A[32 * 128];  // 8KB bf16 swizzled
    __shared__ float muv[128 * 33];                       // 16.5KB f32 TRANSPOSED [col][row+pad]
    __shared__ float2 s_pgb[128];                         // 1KB
    __shared__ float s_bmu[64], s_blv[64], s_pg[64], s_pb[64];
    __shared__ float logit_l[32];
    __shared__ float zpart[4][64];
    __shared__ float klw[4];

    const int t = threadIdx.x, w = t >> 6, l = t & 63, g = l >> 4, li = l & 15;

    if (t < 128) s_pgb[t] = make_float2(pre_g[t], pre_b[t]);
    if (t < 64) { s_bmu[t] = b_mu[t]; s_blv[t] = b_lv[t]; s_pg[t] = post_g[t]; s_pb[t] = post_b[t]; }

    // GEMM1 B-frags: waves 0,1 -> W_mu cols 0-31/32-63; waves 2,3 -> W_lv (cols 64-127 of [mu|lv])
    bf16x8 Wml[2][4];
    {
        const float* Wsrc = (w < 2) ? W_mu : W_lv;
        int cb = 32 * (w & 1) + li;
#pragma unroll
        for (int ntp = 0; ntp < 2; ++ntp)
#pragma unroll
            for (int s = 0; s < 4; ++s) {
                int k0 = 32 * s + 8 * g, c = cb + 16 * ntp;
                bf16x8 f;
#pragma unroll
                for (int j = 0; j < 8; ++j) f[j] = (short)f2bf(Wsrc[(k0 + j) * 64 + c]);
                Wml[ntp][s] = f;
            }
    }
    // out-proj frags: wave w -> h = 32w + (l&31); lane half picks c-window
    const int h = 32 * w + (l & 31);
    const int chalf = l >> 5;
    unsigned int wvo_pk[16];
#pragma unroll
    for (int j = 0; j < 16; ++j) {
        int c = 32 * chalf + 2 * j;
        wvo_pk[j] = (unsigned)f2bf(wvo_ws[c * 128 + h]) | ((unsigned)f2bf(wvo_ws[(c + 1) * 128 + h]) << 16);
    }
    const float bvo_r = bvo_ws[h];
    __syncthreads();

    const int row = t >> 3;          // 0..31
    const int c0 = (t & 7) * 16;     // P0 col group (128 cols)
    const int l0 = (t & 7) * 8;      // P2 col group (64 cols)
    int bn = blockIdx.x * 8;         // 6250 * 8 = 50000 exact

    float x[16], ee[8], qk8[8], trr;
    {   // prologue prefetch
        const float* src = neighbor_feat + ((size_t)bn * NK + row) * NH + c0;
#pragma unroll
        for (int i = 0; i < 4; ++i) {
            float4 v4 = ((const float4*)src)[i];
            x[4 * i] = v4.x; x[4 * i + 1] = v4.y; x[4 * i + 2] = v4.z; x[4 * i + 3] = v4.w;
        }
        const float* ep = eps_g + ((size_t)bn * NK + row) * NL + l0;
        float4 e0 = ((const float4*)ep)[0], e1 = ((const float4*)ep)[1];
        ee[0] = e0.x; ee[1] = e0.y; ee[2] = e0.z; ee[3] = e0.w;
        ee[4] = e1.x; ee[5] = e1.y; ee[6] = e1.z; ee[7] = e1.w;
        const float* qp = qk_ws + (size_t)bn * 64 + l0;
        float4 q0 = ((const float4*)qp)[0], q1 = ((const float4*)qp)[1];
        qk8[0] = q0.x; qk8[1] = q0.y; qk8[2] = q0.z; qk8[3] = q0.w;
        qk8[4] = q1.x; qk8[5] = q1.y; qk8[6] = q1.z; qk8[7] = q1.w;
        trr = trust_mask[(size_t)bn * NK + row];
    }

    float kl_acc = 0.f;
    const f32x4 zero4 = {0.f, 0.f, 0.f, 0.f};

#pragma unroll 1
    for (int i = 0; i < 8; ++i, ++bn) {
        const int bnx = (i < 7) ? bn + 1 : bn;

        // ---- P0: pre-LN -> bf16 A tile; reissue x ----
        float s1 = 0.f;
#pragma unroll
        for (int j = 0; j < 16; ++j) s1 += x[j];
        s1 += __shfl_xor(s1, 1); s1 += __shfl_xor(s1, 2); s1 += __shfl_xor(s1, 4);
        float mean = s1 * (1.f / 128.f);
        float s2 = 0.f;
#pragma unroll
        for (int j = 0; j < 16; ++j) { float d = x[j] - mean; s2 += d * d; }
        s2 += __shfl_xor(s2, 1); s2 += __shfl_xor(s2, 2); s2 += __shfl_xor(s2, 4);
        float inv = rsqrtf(s2 * (1.f / 128.f) + 1e-5f);
        alignas(16) unsigned short yb[16];
#pragma unroll
        for (int j = 0; j < 16; ++j) {
            float2 gb = s_pgb[c0 + j];
            yb[j] = f2bf((x[j] - mean) * inv * gb.x + gb.y);
        }
        {
            int boff = row * 256 + c0 * 2;
            *(int4*)((char*)A + ((boff) ^ ((row & 7) << 4))) = *(int4*)&yb[0];
            *(int4*)((char*)A + ((boff + 16) ^ ((row & 7) << 4))) = *(int4*)&yb[8];
        }
        {
            const float* src = neighbor_feat + ((size_t)bnx * NK + row) * NH + c0;
#pragma unroll
            for (int j = 0; j < 4; ++j) {
                float4 v4 = ((const float4*)src)[j];
                x[4 * j] = v4.x; x[4 * j + 1] = v4.y; x[4 * j + 2] = v4.z; x[4 * j + 3] = v4.w;
            }
        }
        __syncthreads();   // b1

        // ---- P1: GEMM1, wave w -> cols 32w..32w+31 of [mu|lv]; write muv (transposed) ----
        {
            f32x4 acc[2][2];
            acc[0][0] = zero4; acc[0][1] = zero4; acc[1][0] = zero4; acc[1][1] = zero4;
#pragma unroll
            for (int s = 0; s < 4; ++s) {
                bf16x8 A0 = *(const bf16x8*)((const char*)A + ((li * 256 + s * 64 + g * 16) ^ ((li & 7) << 4)));
                bf16x8 A1 = *(const bf16x8*)((const char*)A + (((16 + li) * 256 + s * 64 + g * 16) ^ ((li & 7) << 4)));
#pragma unroll
                for (int ntp = 0; ntp < 2; ++ntp) {
                    acc[0][ntp] = __builtin_amdgcn_mfma_f32_16x16x32_bf16(A0, Wml[ntp][s], acc[0][ntp], 0, 0, 0);
                    acc[1][ntp] = __builtin_amdgcn_mfma_f32_16x16x32_bf16(A1, Wml[ntp][s], acc[1][ntp], 0, 0, 0);
                }
            }
#pragma unroll
            for (int mt = 0; mt < 2; ++mt)
#pragma unroll
                for (int ntp = 0; ntp < 2; ++ntp)
#pragma unroll
                    for (int r = 0; r < 4; ++r)
                        muv[(32 * w + 16 * ntp + li) * 33 + (16 * mt + 4 * g + r)] = acc[mt][ntp][r];
        }
        __syncthreads();   // b2

        // ---- P2: reparam + KL + post-LN + logit partial (scalar muv reads, 2-way banks) ----
        float zr[8];
#pragma unroll
        for (int j = 0; j < 8; ++j) {
            float mu = muv[(l0 + j) * 33 + row] + s_bmu[l0 + j];
            float lv = muv[(64 + l0 + j) * 33 + row] + s_blv[l0 + j];
            float eh = __expf(0.5f * lv);
            kl_acc += 1.f + lv - mu * mu - eh * eh;
            zr[j] = mu + ee[j] * eh;
        }
        {   // reissue eps
            const float* ep = eps_g + ((size_t)bnx * NK + row) * NL + l0;
            float4 e0 = ((const float4*)ep)[0], e1 = ((const float4*)ep)[1];
            ee[0] = e0.x; ee[1] = e0.y; ee[2] = e0.z; ee[3] = e0.w;
            ee[4] = e1.x; ee[5] = e1.y; ee[6] = e1.z; ee[7] = e1.w;
        }
        {
            float zs = 0.f;
#pragma unroll
            for (int j = 0; j < 8; ++j) zs += zr[j];
            zs += __shfl_xor(zs, 1); zs += __shfl_xor(zs, 2); zs += __shfl_xor(zs, 4);
            float zm = zs * (1.f / 64.f);
            float zv = 0.f;
#pragma unroll
            for (int j = 0; j < 8; ++j) { float d = zr[j] - zm; zv += d * d; }
            zv += __shfl_xor(zv, 1); zv += __shfl_xor(zv, 2); zv += __shfl_xor(zv, 4);
            float zi = rsqrtf(zv * (1.f / 64.f) + 1e-5f);
#pragma unroll
            for (int j = 0; j < 8; ++j)
                zr[j] = (zr[j] - zm) * zi * s_pg[l0 + j] + s_pb[l0 + j];
        }
        {   // logit[row]
            float lg = 0.f;
#pragma unroll
            for (int j = 0; j < 8; ++j) lg += zr[j] * qk8[j];
            lg += __shfl_xor(lg, 1); lg += __shfl_xor(lg, 2); lg += __shfl_xor(lg, 4);
            if ((t & 7) == 0) logit_l[row] = lg * 0.125f + __logf(trr + 1e-6f);
        }
        {   // reissue qk + trust
            const float* qp = qk_ws + (size_t)bnx * 64 + l0;
            float4 q0 = ((const float4*)qp)[0], q1 = ((const float4*)qp)[1];
            qk8[0] = q0.x; qk8[1] = q0.y; qk8[2] = q0.z; qk8[3] = q0.w;
            qk8[4] = q1.x; qk8[5] = q1.y; qk8[6] = q1.z; qk8[7] = q1.w;
            trr = trust_mask[(size_t)bnx * NK + row];
        }
        __syncthreads();   // b3

        // ---- P3: wave-parallel softmax + zbar wave-partials ----
        {
            float lgv = logit_l[l & 31];
            float mx = lgv;
            mx = fmaxf(mx, __shfl_xor(mx, 1));  mx = fmaxf(mx, __shfl_xor(mx, 2));
            mx = fmaxf(mx, __shfl_xor(mx, 4));  mx = fmaxf(mx, __shfl_xor(mx, 8));
            mx = fmaxf(mx, __shfl_xor(mx, 16));
            float ev = __expf(lgv - mx);
            float den = ev;
            den += __shfl_xor(den, 1); den += __shfl_xor(den, 2);
            den += __shfl_xor(den, 4); den += __shfl_xor(den, 8);
            den += __shfl_xor(den, 16);
            float att_own = __expf(logit_l[row] - mx) / den;
            float av[8];
#pragma unroll
            for (int j = 0; j < 8; ++j) av[j] = att_own * zr[j];
#pragma unroll
            for (int j = 0; j < 8; ++j) {
                av[j] += __shfl_xor(av[j], 8);
                av[j] += __shfl_xor(av[j], 16);
                av[j] += __shfl_xor(av[j], 32);
            }
            if (l < 8) {
                float4 p0 = {av[0], av[1], av[2], av[3]};
                float4 p1 = {av[4], av[5], av[6], av[7]};
                ((float4*)&zpart[w][8 * l])[0] = p0;
                ((float4*)&zpart[w][8 * l])[1] = p1;
            }
        }
        __syncthreads();   // b4

        // ---- P4: out = zbar @ Wvo + bvo (per-wave h-slice; zpart summed in-loop) ----
        {
            float o = 0.f;
#pragma unroll
            for (int j = 0; j < 16; ++j) {
                int c = 32 * chalf + 2 * j;
                float2 z0 = *(const float2*)&zpart[0][c];
                float2 z1 = *(const float2*)&zpart[1][c];
                float2 z2 = *(const float2*)&zpart[2][c];
                float2 z3 = *(const float2*)&zpart[3][c];
                float zs0 = z0.x + z1.x + z2.x + z3.x;
                float zs1 = z0.y + z1.y + z2.y + z3.y;
                o += zs0 * bflo(wvo_pk[j]) + zs1 * bfhi(wvo_pk[j]);
            }
            o += __shfl_xor(o, 32);
            if (l < 32) out[(size_t)bn * NH + h] = o + bvo_r;
        }
        // no barrier: next P0 writes only A/x; zpart next written after next b3
    }

    // ---- KL reduction ----
#pragma unroll
    for (int msk = 1; msk < 64; msk <<= 1) kl_acc += __shfl_xor(kl_acc, msk);
    if (l == 0) klw[w] = kl_acc;
    __syncthreads();
    if (t == 0) {
        float tot = klw[0] + klw[1] + klw[2] + klw[3];
        atomicAdd(out + (size_t)NB * NH, tot * (-0.5f * 0.001f / ((float)NB * NK)));
    }
}

extern "C" void kernel_launch(void* const* d_in, const int* in_sizes, int n_in,
                              void* d_out, int out_size, void* d_ws, size_t ws_size,
                              hipStream_t stream) {
    const float* self_feat     = (const float*)d_in[0];
    const float* neighbor_feat = (const float*)d_in[1];
    const float* trust_mask    = (const float*)d_in[2];
    const float* eps           = (const float*)d_in[3];
    const float* pre_g  = (const float*)d_in[4];
    const float* pre_b  = (const float*)d_in[5];
    const float* W_mu   = (const float*)d_in[6];
    const float* b_mu   = (const float*)d_in[7];
    const float* W_lv   = (const float*)d_in[8];
    const float* b_lv   = (const float*)d_in[9];
    const float* post_g = (const float*)d_in[10];
    const float* post_b = (const float*)d_in[11];
    const float* W_q    = (const float*)d_in[12];
    const float* b_q    = (const float*)d_in[13];
    const float* W_k    = (const float*)d_in[14];
    const float* W_v    = (const float*)d_in[16];
    const float* b_v    = (const float*)d_in[17];
    const float* W_o    = (const float*)d_in[18];
    const float* b_o    = (const float*)d_in[19];
    float* out = (float*)d_out;

    // ws: qk f32 [NB,64] (12.8MB) | Wvo f32 [64,128] | bvo f32 [128]
    float* qk_ws  = (float*)d_ws;
    float* wvo_ws = qk_ws + (size_t)NB * 64;
    float* bvo_ws = wvo_ws + 64 * 128;

    hipLaunchKernelGGL(kl_zero_kernel, dim3(1), dim3(64), 0, stream, out);
    hipLaunchKernelGGL(wvo_kernel, dim3(1), dim3(256), 0, stream, W_v, W_o, b_v, b_o, wvo_ws, bvo_ws);
    hipLaunchKernelGGL(qk_kernel, dim3((NB + 31) / 32), dim3(256), 0, stream,
                       self_feat, W_q, b_q, W_k, qk_ws);
    hipLaunchKernelGGL(fz10_kernel, dim3(NB / 8), dim3(256), 0, stream,
                       neighbor_feat, trust_mask, eps, pre_g, pre_b,
                       W_mu, b_mu, W_lv, b_lv, post_g, post_b,
                       qk_ws, wvo_ws, bvo_ws, out);
}

// Round 11
// 508.498 us; speedup vs baseline: 1.4537x; 1.0267x over previous
//
#include <hip/hip_runtime.h>
#include <hip/hip_bf16.h>

typedef float f32x4 __attribute__((ext_vector_type(4)));
typedef short bf16x8 __attribute__((ext_vector_type(8)));

#define NB 50000
#define NK 32
#define NH 128
#define NL 64

static __device__ __forceinline__ unsigned short f2bf(float f) {
    unsigned int u = __float_as_uint(f);
    u += 0x7fffu + ((u >> 16) & 1u);
    return (unsigned short)(u >> 16);
}
static __device__ __forceinline__ float bf2f(unsigned short u) {
    return __uint_as_float(((unsigned int)u) << 16);
}

__global__ void kl_zero_kernel(float* out) {
    if (threadIdx.x == 0 && blockIdx.x == 0) out[(size_t)NB * NH] = 0.0f;
}

// ---------------- K0: Wvo = Wv@Wo (f32, ws), bvo = b_v@Wo + b_o ----------------
__global__ void __launch_bounds__(256) wvo_kernel(const float* __restrict__ W_v,
                                                  const float* __restrict__ W_o,
                                                  const float* __restrict__ b_v,
                                                  const float* __restrict__ b_o,
                                                  float* __restrict__ wvo_ws,
                                                  float* __restrict__ bvo_ws)
{
    const int t = threadIdx.x;
    for (int e = t; e < 64 * 128; e += 256) {
        int d = e >> 7, h = e & 127;
        float s = 0.f;
#pragma unroll 8
        for (int c = 0; c < 64; ++c) s += W_v[d * 64 + c] * W_o[c * 128 + h];
        wvo_ws[e] = s;
    }
    if (t < 128) {
        float s = b_o[t];
#pragma unroll 8
        for (int c = 0; c < 64; ++c) s += b_v[c] * W_o[c * 128 + t];
        bvo_ws[t] = s;
    }
}

// ---------------- K1: qk = (self@Wq + b_q) @ Wk^T   (f32 out to ws) ----------------
__global__ void __launch_bounds__(256) qk_kernel(const float* __restrict__ self_feat,
                                                 const float* __restrict__ W_q,
                                                 const float* __restrict__ b_q,
                                                 const float* __restrict__ W_k,
                                                 float* __restrict__ qk_ws)
{
    __shared__ __align__(16) unsigned short A[32 * 128];
    __shared__ __align__(16) unsigned short ZQ[32 * 64];
    const int t = threadIdx.x, w = t >> 6, l = t & 63, g = l >> 4, li = l & 15;

    bf16x8 Bq[4];
#pragma unroll
    for (int s = 0; s < 4; ++s) {
        int k0 = 32 * s + 8 * g, c = li + 16 * w;
        bf16x8 f;
#pragma unroll
        for (int j = 0; j < 8; ++j) f[j] = (short)f2bf(W_q[(k0 + j) * 64 + c]);
        Bq[s] = f;
    }
    bf16x8 Bk[2];
#pragma unroll
    for (int s = 0; s < 2; ++s) {
        int k0 = 32 * s + 8 * g, d = li + 16 * w;
        bf16x8 f;
#pragma unroll
        for (int j = 0; j < 8; ++j) f[j] = (short)f2bf(W_k[d * 64 + k0 + j]);
        Bk[s] = f;
    }
    const float bq = b_q[li + 16 * w];
    const int n0 = blockIdx.x * 32;

    {
        int row = t >> 3, c0 = (t & 7) * 16;
        float x[16];
        if (n0 + row < NB) {
            const float* src = self_feat + (size_t)(n0 + row) * NH + c0;
#pragma unroll
            for (int i = 0; i < 4; ++i) {
                float4 v4 = ((const float4*)src)[i];
                x[4 * i] = v4.x; x[4 * i + 1] = v4.y; x[4 * i + 2] = v4.z; x[4 * i + 3] = v4.w;
            }
        } else {
#pragma unroll
            for (int i = 0; i < 16; ++i) x[i] = 0.f;
        }
        alignas(16) unsigned short yb[16];
#pragma unroll
        for (int i = 0; i < 16; ++i) yb[i] = f2bf(x[i]);
        int boff = row * 256 + c0 * 2;
        *(int4*)((char*)A + ((boff) ^ ((row & 7) << 4))) = *(int4*)&yb[0];
        *(int4*)((char*)A + ((boff + 16) ^ ((row & 7) << 4))) = *(int4*)&yb[8];
    }
    __syncthreads();

    const f32x4 zero4 = {0.f, 0.f, 0.f, 0.f};
    f32x4 acc[2] = {zero4, zero4};
#pragma unroll
    for (int s = 0; s < 4; ++s) {
        bf16x8 A0 = *(const bf16x8*)((const char*)A + ((li * 256 + s * 64 + g * 16) ^ ((li & 7) << 4)));
        bf16x8 A1 = *(const bf16x8*)((const char*)A + (((16 + li) * 256 + s * 64 + g * 16) ^ ((li & 7) << 4)));
        acc[0] = __builtin_amdgcn_mfma_f32_16x16x32_bf16(A0, Bq[s], acc[0], 0, 0, 0);
        acc[1] = __builtin_amdgcn_mfma_f32_16x16x32_bf16(A1, Bq[s], acc[1], 0, 0, 0);
    }
#pragma unroll
    for (int mt = 0; mt < 2; ++mt)
#pragma unroll
        for (int r = 0; r < 4; ++r) {
            int row = 16 * mt + 4 * g + r, c = li + 16 * w;
            *(unsigned short*)((char*)ZQ + ((row * 128 + c * 2) ^ ((row & 7) << 4))) = f2bf(acc[mt][r] + bq);
        }
    __syncthreads();

    f32x4 acc2[2] = {zero4, zero4};
#pragma unroll
    for (int s = 0; s < 2; ++s) {
        bf16x8 A0 = *(const bf16x8*)((const char*)ZQ + ((li * 128 + s * 64 + g * 16) ^ ((li & 7) << 4)));
        bf16x8 A1 = *(const bf16x8*)((const char*)ZQ + (((16 + li) * 128 + s * 64 + g * 16) ^ (((16 + li) & 7) << 4)));
        acc2[0] = __builtin_amdgcn_mfma_f32_16x16x32_bf16(A0, Bk[s], acc2[0], 0, 0, 0);
        acc2[1] = __builtin_amdgcn_mfma_f32_16x16x32_bf16(A1, Bk[s], acc2[1], 0, 0, 0);
    }
#pragma unroll
    for (int mt = 0; mt < 2; ++mt)
#pragma unroll
        for (int r = 0; r < 4; ++r) {
            int row = 16 * mt + 4 * g + r;
            if (n0 + row < NB)
                qk_ws[(size_t)(n0 + row) * 64 + li + 16 * w] = acc2[mt][r];
        }
}

// ---- K2: fused main — 8 nodes/block, 3 barriers/node, batched MFMA out-proj epilogue ----
__global__ void __launch_bounds__(256) fz11_kernel(
    const float* __restrict__ neighbor_feat, const float* __restrict__ trust_mask,
    const float* __restrict__ eps_g,
    const float* __restrict__ pre_g, const float* __restrict__ pre_b,
    const float* __restrict__ W_mu, const float* __restrict__ b_mu,
    const float* __restrict__ W_lv, const float* __restrict__ b_lv,
    const float* __restrict__ post_g, const float* __restrict__ post_b,
    const float* __restrict__ qk_ws, const float* __restrict__ wvo_ws,
    const float* __restrict__ bvo_ws,
    float* __restrict__ out)
{
    __shared__ __align__(16) unsigned short A[32 * 128];  // 8KB bf16 swizzled
    __shared__ float muv[32 * 132];                       // 16.9KB f32 row-major (2-way both sides)
    __shared__ float zparts[8][4][64];                    // 8KB per-node per-wave zbar partials
    __shared__ float2 s_pgb[128];                         // 1KB
    __shared__ float s_bmu[64], s_blv[64], s_pg[64], s_pb[64];
    __shared__ float logit_l[32];
    __shared__ float klw[4];

    const int t = threadIdx.x, w = t >> 6, l = t & 63, g = l >> 4, li = l & 15;

    if (t < 128) s_pgb[t] = make_float2(pre_g[t], pre_b[t]);
    if (t < 64) { s_bmu[t] = b_mu[t]; s_blv[t] = b_lv[t]; s_pg[t] = post_g[t]; s_pb[t] = post_b[t]; }

    // GEMM1 B-frags: waves 0,1 -> W_mu cols 0-31/32-63; waves 2,3 -> W_lv (cols 64-127)
    bf16x8 Wml[2][4];
    {
        const float* Wsrc = (w < 2) ? W_mu : W_lv;
        int cb = 32 * (w & 1) + li;
#pragma unroll
        for (int ntp = 0; ntp < 2; ++ntp)
#pragma unroll
            for (int s = 0; s < 4; ++s) {
                int k0 = 32 * s + 8 * g, c = cb + 16 * ntp;
                bf16x8 f;
#pragma unroll
                for (int j = 0; j < 8; ++j) f[j] = (short)f2bf(Wsrc[(k0 + j) * 64 + c]);
                Wml[ntp][s] = f;
            }
    }
    // out-proj B-frags: wave w covers out cols 32w+16nt+li; k = 32s+8g+j
    bf16x8 Bvo[2][2];
#pragma unroll
    for (int nt = 0; nt < 2; ++nt)
#pragma unroll
        for (int s = 0; s < 2; ++s) {
            int k0 = 32 * s + 8 * g, c = 32 * w + 16 * nt + li;
            bf16x8 f;
#pragma unroll
            for (int j = 0; j < 8; ++j) f[j] = (short)f2bf(wvo_ws[(k0 + j) * 128 + c]);
            Bvo[nt][s] = f;
        }
    const float bvo2[2] = { bvo_ws[32 * w + li], bvo_ws[32 * w + 16 + li] };
    __syncthreads();

    const int row = t >> 3;          // 0..31
    const int c0 = (t & 7) * 16;     // P0 col group (contiguous 16)
    const int a  = t & 7;            // P2 col base: cols a + 8j (scattered)
    const int bn0 = blockIdx.x * 8;  // 6250 * 8 = 50000 exact
    int bn = bn0;

    float x[16], ee[8], qk8[8], trr;
    {   // prologue prefetch
        const float* src = neighbor_feat + ((size_t)bn * NK + row) * NH + c0;
#pragma unroll
        for (int i = 0; i < 4; ++i) {
            float4 v4 = ((const float4*)src)[i];
            x[4 * i] = v4.x; x[4 * i + 1] = v4.y; x[4 * i + 2] = v4.z; x[4 * i + 3] = v4.w;
        }
        const float* ep = eps_g + ((size_t)bn * NK + row) * NL;
        const float* qp = qk_ws + (size_t)bn * 64;
#pragma unroll
        for (int j = 0; j < 8; ++j) { ee[j] = ep[a + 8 * j]; qk8[j] = qp[a + 8 * j]; }
        trr = trust_mask[(size_t)bn * NK + row];
    }

    float kl_acc = 0.f;
    const f32x4 zero4 = {0.f, 0.f, 0.f, 0.f};

#pragma unroll 1
    for (int i = 0; i < 8; ++i, ++bn) {
        const int bnx = (i < 7) ? bn + 1 : bn;

        // ---- P0: pre-LN -> bf16 A tile; reissue x ----
        float s1 = 0.f;
#pragma unroll
        for (int j = 0; j < 16; ++j) s1 += x[j];
        s1 += __shfl_xor(s1, 1); s1 += __shfl_xor(s1, 2); s1 += __shfl_xor(s1, 4);
        float mean = s1 * (1.f / 128.f);
        float s2 = 0.f;
#pragma unroll
        for (int j = 0; j < 16; ++j) { float d = x[j] - mean; s2 += d * d; }
        s2 += __shfl_xor(s2, 1); s2 += __shfl_xor(s2, 2); s2 += __shfl_xor(s2, 4);
        float inv = rsqrtf(s2 * (1.f / 128.f) + 1e-5f);
        alignas(16) unsigned short yb[16];
#pragma unroll
        for (int j = 0; j < 16; ++j) {
            float2 gb = s_pgb[c0 + j];
            yb[j] = f2bf((x[j] - mean) * inv * gb.x + gb.y);
        }
        {
            int boff = row * 256 + c0 * 2;
            *(int4*)((char*)A + ((boff) ^ ((row & 7) << 4))) = *(int4*)&yb[0];
            *(int4*)((char*)A + ((boff + 16) ^ ((row & 7) << 4))) = *(int4*)&yb[8];
        }
        {
            const float* src = neighbor_feat + ((size_t)bnx * NK + row) * NH + c0;
#pragma unroll
            for (int j = 0; j < 4; ++j) {
                float4 v4 = ((const float4*)src)[j];
                x[4 * j] = v4.x; x[4 * j + 1] = v4.y; x[4 * j + 2] = v4.z; x[4 * j + 3] = v4.w;
            }
        }
        __syncthreads();   // b1

        // ---- P1: GEMM1, wave w -> cols 32w..32w+31 of [mu|lv]; write muv (2-way banks) ----
        {
            f32x4 acc[2][2];
            acc[0][0] = zero4; acc[0][1] = zero4; acc[1][0] = zero4; acc[1][1] = zero4;
#pragma unroll
            for (int s = 0; s < 4; ++s) {
                bf16x8 A0 = *(const bf16x8*)((const char*)A + ((li * 256 + s * 64 + g * 16) ^ ((li & 7) << 4)));
                bf16x8 A1 = *(const bf16x8*)((const char*)A + (((16 + li) * 256 + s * 64 + g * 16) ^ ((li & 7) << 4)));
#pragma unroll
                for (int ntp = 0; ntp < 2; ++ntp) {
                    acc[0][ntp] = __builtin_amdgcn_mfma_f32_16x16x32_bf16(A0, Wml[ntp][s], acc[0][ntp], 0, 0, 0);
                    acc[1][ntp] = __builtin_amdgcn_mfma_f32_16x16x32_bf16(A1, Wml[ntp][s], acc[1][ntp], 0, 0, 0);
                }
            }
#pragma unroll
            for (int mt = 0; mt < 2; ++mt)
#pragma unroll
                for (int ntp = 0; ntp < 2; ++ntp)
#pragma unroll
                    for (int r = 0; r < 4; ++r)
                        muv[(16 * mt + 4 * g + r) * 132 + 32 * w + 16 * ntp + li] = acc[mt][ntp][r];
        }
        __syncthreads();   // b2

        // ---- P2: reparam + KL + post-LN + logit (scattered cols a+8j, 2-way banks) ----
        float zr[8];
#pragma unroll
        for (int j = 0; j < 8; ++j) {
            int c = a + 8 * j;
            float mu = muv[row * 132 + c] + s_bmu[c];
            float lv = muv[row * 132 + 64 + c] + s_blv[c];
            float eh = __expf(0.5f * lv);
            kl_acc += 1.f + lv - mu * mu - eh * eh;
            zr[j] = mu + ee[j] * eh;
        }
        {   // reissue eps
            const float* ep = eps_g + ((size_t)bnx * NK + row) * NL;
#pragma unroll
            for (int j = 0; j < 8; ++j) ee[j] = ep[a + 8 * j];
        }
        {
            float zs = 0.f;
#pragma unroll
            for (int j = 0; j < 8; ++j) zs += zr[j];
            zs += __shfl_xor(zs, 1); zs += __shfl_xor(zs, 2); zs += __shfl_xor(zs, 4);
            float zm = zs * (1.f / 64.f);
            float zv = 0.f;
#pragma unroll
            for (int j = 0; j < 8; ++j) { float d = zr[j] - zm; zv += d * d; }
            zv += __shfl_xor(zv, 1); zv += __shfl_xor(zv, 2); zv += __shfl_xor(zv, 4);
            float zi = rsqrtf(zv * (1.f / 64.f) + 1e-5f);
#pragma unroll
            for (int j = 0; j < 8; ++j) {
                int c = a + 8 * j;
                zr[j] = (zr[j] - zm) * zi * s_pg[c] + s_pb[c];
            }
        }
        {   // logit[row]
            float lg = 0.f;
#pragma unroll
            for (int j = 0; j < 8; ++j) lg += zr[j] * qk8[j];
            lg += __shfl_xor(lg, 1); lg += __shfl_xor(lg, 2); lg += __shfl_xor(lg, 4);
            if (a == 0) logit_l[row] = lg * 0.125f + __logf(trr + 1e-6f);
        }
        {   // reissue qk + trust
            const float* qp = qk_ws + (size_t)bnx * 64;
#pragma unroll
            for (int j = 0; j < 8; ++j) qk8[j] = qp[a + 8 * j];
            trr = trust_mask[(size_t)bnx * NK + row];
        }
        __syncthreads();   // b3

        // ---- P3: wave-parallel softmax + per-wave zbar partials (no barrier after) ----
        {
            float lgv = logit_l[l & 31];
            float mx = lgv;
            mx = fmaxf(mx, __shfl_xor(mx, 1));  mx = fmaxf(mx, __shfl_xor(mx, 2));
            mx = fmaxf(mx, __shfl_xor(mx, 4));  mx = fmaxf(mx, __shfl_xor(mx, 8));
            mx = fmaxf(mx, __shfl_xor(mx, 16));
            float ev = __expf(lgv - mx);
            float den = ev;
            den += __shfl_xor(den, 1); den += __shfl_xor(den, 2);
            den += __shfl_xor(den, 4); den += __shfl_xor(den, 8);
            den += __shfl_xor(den, 16);
            float att_own = __expf(logit_l[row] - mx) / den;
            float av[8];
#pragma unroll
            for (int j = 0; j < 8; ++j) av[j] = att_own * zr[j];
#pragma unroll
            for (int j = 0; j < 8; ++j) {
                av[j] += __shfl_xor(av[j], 8);
                av[j] += __shfl_xor(av[j], 16);
                av[j] += __shfl_xor(av[j], 32);
            }
            if (l < 8) {
#pragma unroll
                for (int j = 0; j < 8; ++j) zparts[i][w][l + 8 * j] = av[j];
            }
        }
        // no barrier: next P0 writes A only; zparts[i] read only after epilogue barrier
    }
    __syncthreads();   // epilogue barrier

    // ---- Epilogue: out[0..7] = zbar @ Wvo + bvo via 2 MFMA tiles (hi/lo split A) ----
    {
        bf16x8 Ahi[2], Alo[2];
#pragma unroll
        for (int s = 0; s < 2; ++s)
#pragma unroll
            for (int j = 0; j < 8; ++j) {
                float z = 0.f;
                if (li < 8) {
                    int c = 32 * s + 8 * g + j;
                    z = zparts[li][0][c] + zparts[li][1][c] + zparts[li][2][c] + zparts[li][3][c];
                }
                unsigned short hi = f2bf(z);
                Ahi[s][j] = (short)hi;
                Alo[s][j] = (short)f2bf(z - bf2f(hi));
            }
        f32x4 accE[2] = {zero4, zero4};
#pragma unroll
        for (int s = 0; s < 2; ++s)
#pragma unroll
            for (int nt = 0; nt < 2; ++nt) {
                accE[nt] = __builtin_amdgcn_mfma_f32_16x16x32_bf16(Ahi[s], Bvo[nt][s], accE[nt], 0, 0, 0);
                accE[nt] = __builtin_amdgcn_mfma_f32_16x16x32_bf16(Alo[s], Bvo[nt][s], accE[nt], 0, 0, 0);
            }
#pragma unroll
        for (int nt = 0; nt < 2; ++nt)
#pragma unroll
            for (int r = 0; r < 4; ++r) {
                int rr = 4 * g + r;
                if (rr < 8)
                    out[(size_t)(bn0 + rr) * NH + 32 * w + 16 * nt + li] = accE[nt][r] + bvo2[nt];
            }
    }

    // ---- KL reduction ----
#pragma unroll
    for (int msk = 1; msk < 64; msk <<= 1) kl_acc += __shfl_xor(kl_acc, msk);
    if (l == 0) klw[w] = kl_acc;
    __syncthreads();
    if (t == 0) {
        float tot = klw[0] + klw[1] + klw[2] + klw[3];
        atomicAdd(out + (size_t)NB * NH, tot * (-0.5f * 0.001f / ((float)NB * NK)));
    }
}

extern "C" void kernel_launch(void* const* d_in, const int* in_sizes, int n_in,
                              void* d_out, int out_size, void* d_ws, size_t ws_size,
                              hipStream_t stream) {
    const float* self_feat     = (const float*)d_in[0];
    const float* neighbor_feat = (const float*)d_in[1];
    const float* trust_mask    = (const float*)d_in[2];
    const float* eps           = (const float*)d_in[3];
    const float* pre_g  = (const float*)d_in[4];
    const float* pre_b  = (const float*)d_in[5];
    const float* W_mu   = (const float*)d_in[6];
    const float* b_mu   = (const float*)d_in[7];
    const float* W_lv   = (const float*)d_in[8];
    const float* b_lv   = (const float*)d_in[9];
    const float* post_g = (const float*)d_in[10];
    const float* post_b = (const float*)d_in[11];
    const float* W_q    = (const float*)d_in[12];
    const float* b_q    = (const float*)d_in[13];
    const float* W_k    = (const float*)d_in[14];
    const float* W_v    = (const float*)d_in[16];
    const float* b_v    = (const float*)d_in[17];
    const float* W_o    = (const float*)d_in[18];
    const float* b_o    = (const float*)d_in[19];
    float* out = (float*)d_out;

    // ws: qk f32 [NB,64] (12.8MB) | Wvo f32 [64,128] | bvo f32 [128]
    float* qk_ws  = (float*)d_ws;
    float* wvo_ws = qk_ws + (size_t)NB * 64;
    float* bvo_ws = wvo_ws + 64 * 128;

    hipLaunchKernelGGL(kl_zero_kernel, dim3(1), dim3(64), 0, stream, out);
    hipLaunchKernelGGL(wvo_kernel, dim3(1), dim3(256), 0, stream, W_v, W_o, b_v, b_o, wvo_ws, bvo_ws);
    hipLaunchKernelGGL(qk_kernel, dim3((NB + 31) / 32), dim3(256), 0, stream,
                       self_feat, W_q, b_q, W_k, qk_ws);
    hipLaunchKernelGGL(fz11_kernel, dim3(NB / 8), dim3(256), 0, stream,
                       neighbor_feat, trust_mask, eps, pre_g, pre_b,
                       W_mu, b_mu, W_lv, b_lv, post_g, post_b,
                       qk_ws, wvo_ws, bvo_ws, out);
}